// Round 1
// baseline (22.675 us; speedup 1.0000x reference)
//
#include <hip/hip_runtime.h>
#include <math.h>

// Problem constants (probs/targets: (32,1,512,512) fp32)
#define NS 32              // samples
#define NELEM 262144       // elements per sample = 1*512*512
#define PB 64              // partial blocks per sample
#define CHUNK (NELEM / PB) // 4096 elements per block
#define TPB 256            // threads per block (4 waves)

// Workspace float-offset layout (all fit well under typical ws_size)
#define SP (NS * PB)       // 2048 partials
#define OFF_S1   0
#define OFF_S2   (SP * 1)
#define OFF_DOT  (SP * 2)
#define OFF_MX   (SP * 3)
#define OFF_CLE  (SP * 4)  // int
#define OFF_CNT  (SP * 5)  // int
#define OFF_GT   (SP * 6)  // int
#define OFF_SCORE (SP * 7) // 32 floats

__device__ __forceinline__ void combine_max(float& mx, int& cnt, int& gt,
                                            float mx2, int cnt2, int gt2) {
    if (mx2 > mx) { mx = mx2; cnt = cnt2; gt = gt2; }
    else if (mx2 == mx) { cnt += cnt2; gt += gt2; }
}

__global__ __launch_bounds__(TPB) void k_partial(const float* __restrict__ probs,
                                                 const float* __restrict__ tgts,
                                                 float* __restrict__ wsf,
                                                 int* __restrict__ wsi) {
    const int b = blockIdx.x;
    const int s = b / PB;
    const int c = b % PB;
    const size_t base = (size_t)s * NELEM + (size_t)c * CHUNK;
    const float4* __restrict__ p4 = (const float4*)(probs + base);
    const float4* __restrict__ t4 = (const float4*)(tgts + base);
    const int t = threadIdx.x;

    float s1 = 0.f, s2 = 0.f, dot = 0.f;
    int cle = 0, cnt = 0, gt = 0;
    float mx = -INFINITY;

    auto upd = [&](float pv, float tv) {
        s1 += pv;
        s2 += tv;
        dot += pv * tv;
        cle += (pv <= 0.5f) ? 1 : 0;
        if (tv > mx)       { mx = tv; cnt = 1; gt = (pv > 0.5f) ? 1 : 0; }
        else if (tv == mx) { cnt += 1; gt += (pv > 0.5f) ? 1 : 0; }
    };

#pragma unroll
    for (int k = 0; k < CHUNK / 4 / TPB; ++k) {   // 4 iterations
        float4 p = p4[t + k * TPB];
        float4 q = t4[t + k * TPB];
        upd(p.x, q.x); upd(p.y, q.y); upd(p.z, q.z); upd(p.w, q.w);
    }

    // 64-lane wave reduction (xor butterfly — well-defined for all lanes)
#pragma unroll
    for (int off = 32; off; off >>= 1) {
        s1  += __shfl_xor(s1, off);
        s2  += __shfl_xor(s2, off);
        dot += __shfl_xor(dot, off);
        cle += __shfl_xor(cle, off);
        float m2 = __shfl_xor(mx, off);
        int   c2 = __shfl_xor(cnt, off);
        int   g2 = __shfl_xor(gt, off);
        combine_max(mx, cnt, gt, m2, c2, g2);
    }

    // cross-wave via LDS (4 waves)
    __shared__ float ls1[4], ls2[4], ldot[4], lmx[4];
    __shared__ int   lcle[4], lcnt[4], lgt[4];
    const int w = t >> 6, lane = t & 63;
    if (lane == 0) {
        ls1[w] = s1; ls2[w] = s2; ldot[w] = dot; lmx[w] = mx;
        lcle[w] = cle; lcnt[w] = cnt; lgt[w] = gt;
    }
    __syncthreads();
    if (t == 0) {
#pragma unroll
        for (int w2 = 1; w2 < TPB / 64; ++w2) {
            s1 += ls1[w2]; s2 += ls2[w2]; dot += ldot[w2]; cle += lcle[w2];
            combine_max(mx, cnt, gt, lmx[w2], lcnt[w2], lgt[w2]);
        }
        wsf[OFF_S1  + b] = s1;
        wsf[OFF_S2  + b] = s2;
        wsf[OFF_DOT + b] = dot;
        wsf[OFF_MX  + b] = mx;
        wsi[OFF_CLE + b] = cle;
        wsi[OFF_CNT + b] = cnt;
        wsi[OFF_GT  + b] = gt;
    }
}

__global__ __launch_bounds__(64) void k_sample(const float* __restrict__ wsf,
                                               const int* __restrict__ wsi,
                                               float* __restrict__ scores) {
    const int s = blockIdx.x;
    const int lane = threadIdx.x;          // PB == 64 exactly
    const int idx = s * PB + lane;

    float s1  = wsf[OFF_S1  + idx];
    float s2  = wsf[OFF_S2  + idx];
    float dot = wsf[OFF_DOT + idx];
    float mx  = wsf[OFF_MX  + idx];
    int   cle = wsi[OFF_CLE + idx];
    int   cnt = wsi[OFF_CNT + idx];
    int   gt  = wsi[OFF_GT  + idx];

#pragma unroll
    for (int off = 32; off; off >>= 1) {
        s1  += __shfl_xor(s1, off);
        s2  += __shfl_xor(s2, off);
        dot += __shfl_xor(dot, off);
        cle += __shfl_xor(cle, off);
        float m2 = __shfl_xor(mx, off);
        int   c2 = __shfl_xor(cnt, off);
        int   g2 = __shfl_xor(gt, off);
        combine_max(mx, cnt, gt, m2, c2, g2);
    }

    if (lane == 0) {
        // corr = count(m1<=0.5) - cnt_at_max + 2*gt_at_max  (tie-safe)
        long long corr = (long long)cle - (long long)cnt + 2LL * (long long)gt;
        float score = 2.0f * (dot + 1.0f) / (s1 + s2 + 1.0f);
        // acc = corr / probs.shape[1] = corr / 1  -> acc==1.0 iff corr==1
        if (corr == 1) score = 1.0f;
        scores[s] = 1.0f - score;
    }
}

__global__ __launch_bounds__(64) void k_mean(const float* __restrict__ scores,
                                             float* __restrict__ out) {
    const int lane = threadIdx.x;
    float v = (lane < NS) ? scores[lane] : 0.0f;
#pragma unroll
    for (int off = 32; off; off >>= 1) v += __shfl_xor(v, off);
    if (lane == 0) out[0] = v / (float)NS;
}

extern "C" void kernel_launch(void* const* d_in, const int* in_sizes, int n_in,
                              void* d_out, int out_size, void* d_ws, size_t ws_size,
                              hipStream_t stream) {
    const float* probs = (const float*)d_in[0];
    const float* tgts  = (const float*)d_in[1];
    float* wsf = (float*)d_ws;
    int*   wsi = (int*)d_ws;
    float* out = (float*)d_out;

    k_partial<<<NS * PB, TPB, 0, stream>>>(probs, tgts, wsf, wsi);
    k_sample<<<NS, 64, 0, stream>>>(wsf, wsi, wsf + OFF_SCORE);
    k_mean<<<1, 64, 0, stream>>>(wsf + OFF_SCORE, out);
}